// Round 7
// baseline (413.036 us; speedup 1.0000x reference)
//
#include <hip/hip_runtime.h>
#include <hip/hip_bf16.h>

#define SEQ 2048

typedef unsigned short ushort_t;
typedef __attribute__((ext_vector_type(8))) short short8;
typedef __attribute__((ext_vector_type(4))) float f32x4;

__device__ __forceinline__ ushort_t f2bf(float f) {
    __hip_bfloat16 h = __float2bfloat16(f);
    return *reinterpret_cast<ushort_t*>(&h);
}

__device__ __forceinline__ void st(float* p, float v) { *p = v; }
__device__ __forceinline__ void st(ushort_t* p, float v) { *p = f2bf(v); }

// async global->LDS, 16B per lane, wave-uniform LDS base + lane*16
__device__ __forceinline__ void gload16(const ushort_t* g, ushort_t* l) {
    __builtin_amdgcn_global_load_lds(
        (const __attribute__((address_space(1))) unsigned int*)g,
        (__attribute__((address_space(3))) unsigned int*)l, 16, 0, 0);
}

// ---- fp32 -> bf16 pack, up to 5 segments (sizes in float4 units) ----
__global__ void cvt_bf_kernel(const float* __restrict__ s0, ushort_t* __restrict__ d0, int n0,
                              const float* __restrict__ s1, ushort_t* __restrict__ d1, int n1,
                              const float* __restrict__ s2, ushort_t* __restrict__ d2, int n2,
                              const float* __restrict__ s3, ushort_t* __restrict__ d3, int n3,
                              const float* __restrict__ s4, ushort_t* __restrict__ d4) {
    int u = blockIdx.x * 256 + threadIdx.x;
    const float* s; ushort_t* d;
    if (u < n0) { s = s0; d = d0; }
    else if ((u -= n0) < n1) { s = s1; d = d1; }
    else if ((u -= n1) < n2) { s = s2; d = d2; }
    else if ((u -= n2) < n3) { s = s3; d = d3; }
    else { u -= n3; s = s4; d = d4; }
    float4 a = ((const float4*)s)[u];
    union { ushort_t us[4]; unsigned long long ll; } pk;
    pk.us[0] = f2bf(a.x); pk.us[1] = f2bf(a.y);
    pk.us[2] = f2bf(a.z); pk.us[3] = f2bf(a.w);
    ((unsigned long long*)d)[u] = pk.ll;
}

// ---- 128x128 m97-style GEMM (QKV / Wo): BK=64, gload16, XOR swizzle ----
template <bool SILU, typename TC>
__global__ __launch_bounds__(256) void mfma_gemm_kernel(
    const ushort_t* __restrict__ A, const ushort_t* __restrict__ W,
    const float* __restrict__ bias0, const float* __restrict__ bias1,
    const float* __restrict__ bias2, int sp1, int sp2,
    TC* __restrict__ C, int M, int N, int Kd, int NBX) {
    __shared__ __align__(16) ushort_t As[128 * 64];
    __shared__ __align__(16) ushort_t Bs[128 * 64];
    const int tid = threadIdx.x;
    const int w = tid >> 6, lane = tid & 63, l15 = lane & 15, quad = lane >> 4;
    const int nwg = gridDim.x;
    const int qq = nwg >> 3;
    const int bid = blockIdx.x;
    const int sw = (bid & 7) * qq + (bid >> 3);
    const int m0 = (sw / NBX) * 128, n0 = (sw % NBX) * 128;
    const int rw = (w >> 1) * 64, cw = (w & 1) * 64;
    const int rA = w * 32 + (lane >> 3);
    const int cch = ((lane & 7) ^ (lane >> 3)) * 8;

    f32x4 acc[4][4];
#pragma unroll
    for (int mt = 0; mt < 4; ++mt)
#pragma unroll
        for (int nt = 0; nt < 4; ++nt) acc[mt][nt] = (f32x4){0.f, 0.f, 0.f, 0.f};

    for (int k0 = 0; k0 < Kd; k0 += 64) {
#pragma unroll
        for (int c = 0; c < 4; ++c) {
            gload16(&A[(size_t)(m0 + rA + c * 8) * Kd + k0 + cch],
                    &As[(w * 4 + c) * 512]);
            gload16(&W[(size_t)(n0 + rA + c * 8) * Kd + k0 + cch],
                    &Bs[(w * 4 + c) * 512]);
        }
        __syncthreads();
#pragma unroll
        for (int kc = 0; kc < 2; ++kc) {
            short8 af[4], bfr[4];
#pragma unroll
            for (int mt = 0; mt < 4; ++mt) {
                int row = rw + mt * 16 + l15;
                int slot = (kc * 4 + quad) ^ (row & 7);
                af[mt] = *(const short8*)&As[row * 64 + slot * 8];
            }
#pragma unroll
            for (int nt = 0; nt < 4; ++nt) {
                int row = cw + nt * 16 + l15;
                int slot = (kc * 4 + quad) ^ (row & 7);
                bfr[nt] = *(const short8*)&Bs[row * 64 + slot * 8];
            }
#pragma unroll
            for (int mt = 0; mt < 4; ++mt)
#pragma unroll
                for (int nt = 0; nt < 4; ++nt)
                    acc[mt][nt] = __builtin_amdgcn_mfma_f32_16x16x32_bf16(
                        af[mt], bfr[nt], acc[mt][nt], 0, 0, 0);
        }
        __syncthreads();
    }
#pragma unroll
    for (int nt = 0; nt < 4; ++nt) {
        int col = n0 + cw + nt * 16 + l15;
        float bb = col < sp1 ? bias0[col]
                 : (col < sp2 ? bias1[col - sp1] : bias2[col - sp2]);
#pragma unroll
        for (int mt = 0; mt < 4; ++mt)
#pragma unroll
            for (int r = 0; r < 4; ++r) {
                int row = m0 + rw + mt * 16 + quad * 4 + r;
                float v = acc[mt][nt][r] + bb;
                if (SILU) v = v / (1.f + __expf(-v));
                st(&C[(size_t)row * N + col], v);
            }
    }
}

// ---- staging for the pipelined GEMM: per wave, 4 A-chunks + 2 B-chunks ----
__device__ __forceinline__ void stage_pipe(
    const ushort_t* __restrict__ A, const ushort_t* __restrict__ W,
    ushort_t* Abuf, ushort_t* Bbuf, int m0, int n0, int Kd, int kk,
    int w, int lr, int cch) {
#pragma unroll
    for (int cc = 0; cc < 4; ++cc)
        gload16(&A[(size_t)(m0 + w * 32 + cc * 8 + lr) * Kd + kk + cch],
                &Abuf[(w * 4 + cc) * 512]);
#pragma unroll
    for (int cc = 0; cc < 2; ++cc)
        gload16(&W[(size_t)(n0 + w * 16 + cc * 8 + lr) * Kd + kk + cch],
                &Bbuf[(w * 2 + cc) * 512]);
}

// ---- pipelined GEMM for W1/W2: BM=256 x BN=128, BK=64, 512 thr (8 waves 2x4),
// 3 LDS buffers, depth-2 prefetch with COUNTED vmcnt (never drains to 0 in
// steady state), raw s_barrier + sched_barrier(0) fences, T2 swizzle, T5
// setprio. Each wave issues exactly 6 gload16 per K-tile; vmcnt(12) before
// barrier#2 proves this wave's tile-(t+1) share landed; the barrier then
// proves all waves' shares landed. Barrier#1 (post-MFMA) fences re-staging. ----
template <bool SILU, typename TC>
__global__ __launch_bounds__(512) void mfma_gemm_pipe(
    const ushort_t* __restrict__ A, const ushort_t* __restrict__ W,
    const float* __restrict__ bias, TC* __restrict__ C,
    int M, int N, int Kd, int NBX) {
    __shared__ __align__(16) ushort_t Ap[3][256 * 64];
    __shared__ __align__(16) ushort_t Bp[3][128 * 64];
    const int tid = threadIdx.x;
    const int w = tid >> 6, lane = tid & 63, l15 = lane & 15, quad = lane >> 4;
    const int wm = w >> 2, wn = w & 3;
    const int nwg = gridDim.x, qq = nwg >> 3, bid = blockIdx.x;
    const int sw = (bid & 7) * qq + (bid >> 3);
    const int m0 = (sw / NBX) * 256, n0 = (sw % NBX) * 128;
    const int rw = wm * 128, cw = wn * 32;
    const int lr = lane >> 3;
    const int cch = ((lane & 7) ^ lr) * 8;
    const int nt = Kd >> 6;

    f32x4 acc[8][2];
#pragma unroll
    for (int mt = 0; mt < 8; ++mt)
#pragma unroll
        for (int n2 = 0; n2 < 2; ++n2) acc[mt][n2] = (f32x4){0.f, 0.f, 0.f, 0.f};

    stage_pipe(A, W, Ap[0], Bp[0], m0, n0, Kd, 0, w, lr, cch);
    stage_pipe(A, W, Ap[1], Bp[1], m0, n0, Kd, 64, w, lr, cch);
    stage_pipe(A, W, Ap[2], Bp[2], m0, n0, Kd, 128, w, lr, cch);
    asm volatile("s_waitcnt vmcnt(12)" ::: "memory");
    __builtin_amdgcn_sched_barrier(0);
    __builtin_amdgcn_s_barrier();

    for (int t = 0; t < nt; ++t) {
        const int c = t % 3;
        const ushort_t* As = Ap[c];
        const ushort_t* Bs = Bp[c];
        __builtin_amdgcn_sched_barrier(0);
        short8 bfr[2][2];
#pragma unroll
        for (int n2 = 0; n2 < 2; ++n2) {
            int row = cw + n2 * 16 + l15;
#pragma unroll
            for (int kc = 0; kc < 2; ++kc)
                bfr[n2][kc] = *(const short8*)
                    &Bs[row * 64 + (((kc * 4 + quad) ^ (row & 7)) * 8)];
        }
#pragma unroll
        for (int mt = 0; mt < 8; ++mt) {
            int row = rw + mt * 16 + l15;
            short8 a0 = *(const short8*)&As[row * 64 + (((quad) ^ (row & 7)) * 8)];
            short8 a1 = *(const short8*)&As[row * 64 + (((4 + quad) ^ (row & 7)) * 8)];
            __builtin_amdgcn_s_setprio(1);
            acc[mt][0] = __builtin_amdgcn_mfma_f32_16x16x32_bf16(a0, bfr[0][0], acc[mt][0], 0, 0, 0);
            acc[mt][0] = __builtin_amdgcn_mfma_f32_16x16x32_bf16(a1, bfr[0][1], acc[mt][0], 0, 0, 0);
            acc[mt][1] = __builtin_amdgcn_mfma_f32_16x16x32_bf16(a0, bfr[1][0], acc[mt][1], 0, 0, 0);
            acc[mt][1] = __builtin_amdgcn_mfma_f32_16x16x32_bf16(a1, bfr[1][1], acc[mt][1], 0, 0, 0);
            __builtin_amdgcn_s_setprio(0);
        }
        if (t + 1 == nt) break;
        __builtin_amdgcn_sched_barrier(0);
        __builtin_amdgcn_s_barrier();       // #1: all waves done reading buf c
        if (t + 3 < nt) {
            stage_pipe(A, W, Ap[c], Bp[c], m0, n0, Kd, (t + 3) << 6, w, lr, cch);
            asm volatile("s_waitcnt vmcnt(12)" ::: "memory");
        } else if (t + 2 < nt) {
            asm volatile("s_waitcnt vmcnt(6)" ::: "memory");
        } else {
            asm volatile("s_waitcnt vmcnt(0)" ::: "memory");
        }
        __builtin_amdgcn_sched_barrier(0);
        __builtin_amdgcn_s_barrier();       // #2: buf (t+1)%3 ready
    }

#pragma unroll
    for (int n2 = 0; n2 < 2; ++n2) {
        int col = n0 + cw + n2 * 16 + l15;
        float bb = bias[col];
#pragma unroll
        for (int mt = 0; mt < 8; ++mt)
#pragma unroll
            for (int r = 0; r < 4; ++r) {
                int row = m0 + rw + mt * 16 + quad * 4 + r;
                float v = acc[mt][n2][r] + bb;
                if (SILU) v = v / (1.f + __expf(-v));
                st(&C[(size_t)row * N + col], v);
            }
    }
}

// ---- fused RoPE + V-transpose (both read qkv_f32, independent outputs) ----
// blocks [0,2048): rope row s=bx ; blocks [2048,2304): V-transpose 64x64 tile.
__global__ void prep_kernel(const float* __restrict__ qkv,
                            ushort_t* __restrict__ qb, ushort_t* __restrict__ kb,
                            ushort_t* __restrict__ vT) {
    const int bx = blockIdx.x;
    const int tid = threadIdx.x;
    if (bx < 2048) {
        const int s = bx;
        const float t = (float)s;
        const float qs = 0.08838834764831845f;   // 1/sqrt(128)
        for (int p = tid; p < 768; p += 256) {
            int idx = p & 63;
            float invf = exp2f(-(float)idx * 0.20762050593f);
            float ang = t * invf;
            float c = cosf(ang), sn = sinf(ang);
            if (p < 512) {
                int h = p >> 6;
                const float* src = qkv + (size_t)s * 2048 + h * 128 + idx;
                ushort_t* dst = qb + (size_t)s * 1024 + h * 128 + idx;
                float x1 = src[0], x2 = src[64];
                dst[0] = f2bf((x1 * c - x2 * sn) * qs);
                dst[64] = f2bf((x2 * c + x1 * sn) * qs);
            } else {
                int h = (p - 512) >> 6;
                const float* src = qkv + (size_t)s * 2048 + 1024 + h * 128 + idx;
                ushort_t* dst = kb + (size_t)s * 512 + h * 128 + idx;
                float x1 = src[0], x2 = src[64];
                dst[0] = f2bf(x1 * c - x2 * sn);
                dst[64] = f2bf(x2 * c + x1 * sn);
            }
        }
    } else {
        __shared__ __align__(16) ushort_t t[64][72];
        const int u = bx - 2048;
        const int s0 = (u & 31) * 64, d0 = (u >> 5) * 64;
#pragma unroll
        for (int it = 0; it < 4; ++it) {
            int uu = tid + it * 256;
            int r = uu >> 4, c4 = uu & 15;
            float4 a = *(const float4*)&qkv[(size_t)(s0 + r) * 2048 + 1536 + d0 + c4 * 4];
            union { ushort_t us[4]; unsigned long long ll; } pk;
            pk.us[0] = f2bf(a.x); pk.us[1] = f2bf(a.y);
            pk.us[2] = f2bf(a.z); pk.us[3] = f2bf(a.w);
            *(unsigned long long*)&t[r][c4 * 4] = pk.ll;
        }
        __syncthreads();
#pragma unroll
        for (int it = 0; it < 2; ++it) {
            int uu = tid + it * 256;
            int r = uu >> 3, c8 = uu & 7;
            short8 o;
            ushort_t* op = (ushort_t*)&o;
#pragma unroll
            for (int i = 0; i < 8; ++i) op[i] = t[c8 * 8 + i][r];
            *(short8*)&vT[(size_t)(d0 + r) * 2048 + s0 + c8 * 8] = o;
        }
    }
}

// MFMA flash attention, fixed-base softmax + XOR-swizzled K/V LDS (unchanged).
__global__ __launch_bounds__(256, 2) void mfma_attn_kernel(
    const ushort_t* __restrict__ qb, const ushort_t* __restrict__ kb,
    const ushort_t* __restrict__ vT, float* __restrict__ part) {
    const int tid = threadIdx.x;
    const int w = tid >> 6;
    const int lane = tid & 63;
    const int l15 = lane & 15;
    const int quad = lane >> 4;
    const int bx = blockIdx.x;
    const int pr = bx >> 3;
    const int g = (bx >> 1) & 3;
    const int h = (bx & 1) * 4 + w;

    const ushort_t* vtg = vT + (size_t)g * 128 * 2048;

    __shared__ __align__(16) ushort_t Ks[64 * 128];
    __shared__ __align__(16) ushort_t Vs[128 * 64];
    __shared__ __align__(16) ushort_t P_lds[4][16][72];

#pragma unroll 1
    for (int half = 0; half < 2; ++half) {
        const int p = half ? (127 - pr) : pr;
        const int i0 = p << 4;
        const int jmax = p >> 2;
        const int rbase = (p & 3) << 4;

        short8 aq[4];
        {
            const ushort_t* qrow = qb + (size_t)(i0 + l15) * 1024 + h * 128 + quad * 8;
#pragma unroll
            for (int kc = 0; kc < 4; ++kc) aq[kc] = *(const short8*)(qrow + kc * 32);
        }
        f32x4 oacc[8];
#pragma unroll
        for (int nt = 0; nt < 8; ++nt) oacc[nt] = (f32x4){0.f, 0.f, 0.f, 0.f};
        float l_part[4] = {0.f, 0.f, 0.f, 0.f};

        short8 kreg[4], vreg[4];
#pragma unroll
        for (int it = 0; it < 4; ++it) {
            int fl = it * 256 + tid;
            int r = fl >> 4, c8 = fl & 15;
            kreg[it] = *(const short8*)&kb[(size_t)r * 512 + g * 128 + c8 * 8];
        }
#pragma unroll
        for (int it = 0; it < 4; ++it) {
            int fl = it * 256 + tid;
            int r = fl >> 3, c8 = fl & 7;
            vreg[it] = *(const short8*)&vtg[(size_t)r * 2048 + c8 * 8];
        }

        for (int jt = 0; jt <= jmax; ++jt) {
            __syncthreads();
#pragma unroll
            for (int it = 0; it < 4; ++it) {
                int fl = it * 256 + tid;
                int r = fl >> 4, c8 = fl & 15;
                *(short8*)&Ks[r * 128 + ((c8 ^ (r & 7)) * 8)] = kreg[it];
            }
#pragma unroll
            for (int it = 0; it < 4; ++it) {
                int fl = it * 256 + tid;
                int r = fl >> 3, c8 = fl & 7;
                *(short8*)&Vs[r * 64 + ((c8 ^ (r & 7)) * 8)] = vreg[it];
            }
            __syncthreads();
            if (jt < jmax) {
                const int j1 = (jt + 1) << 6;
#pragma unroll
                for (int it = 0; it < 4; ++it) {
                    int fl = it * 256 + tid;
                    int r = fl >> 4, c8 = fl & 15;
                    kreg[it] = *(const short8*)&kb[(size_t)(j1 + r) * 512 + g * 128 + c8 * 8];
                }
#pragma unroll
                for (int it = 0; it < 4; ++it) {
                    int fl = it * 256 + tid;
                    int r = fl >> 3, c8 = fl & 7;
                    vreg[it] = *(const short8*)&vtg[(size_t)r * 2048 + j1 + c8 * 8];
                }
            }
            f32x4 sacc[4];
#pragma unroll
            for (int nt = 0; nt < 4; ++nt) sacc[nt] = (f32x4){0.f, 0.f, 0.f, 0.f};
#pragma unroll
            for (int nt = 0; nt < 4; ++nt) {
                const ushort_t* krow = &Ks[(nt * 16 + l15) * 128];
                const int sw = l15 & 7;
#pragma unroll
                for (int kc = 0; kc < 4; ++kc) {
                    short8 bk = *(const short8*)(krow + (((kc * 4 + quad) ^ sw) * 8));
                    sacc[nt] = __builtin_amdgcn_mfma_f32_16x16x32_bf16(
                        aq[kc], bk, sacc[nt], 0, 0, 0);
                }
            }
            if (jt == jmax) {
#pragma unroll
                for (int nt = 0; nt < 4; ++nt) {
                    int colg = nt * 16 + l15;
#pragma unroll
                    for (int r = 0; r < 4; ++r) {
                        int rowg = rbase + quad * 4 + r;
                        if (colg > rowg) sacc[nt][r] = -1e30f;
                    }
                }
            }
#pragma unroll
            for (int nt = 0; nt < 4; ++nt)
#pragma unroll
                for (int r = 0; r < 4; ++r) {
                    float e = __expf(sacc[nt][r] - 14.f);
                    sacc[nt][r] = e;
                    l_part[r] += e;
                }
#pragma unroll
            for (int nt = 0; nt < 4; ++nt)
#pragma unroll
                for (int r = 0; r < 4; ++r)
                    P_lds[w][quad * 4 + r][nt * 16 + l15] = f2bf(sacc[nt][r]);
            asm volatile("s_waitcnt lgkmcnt(0)" ::: "memory");
            __builtin_amdgcn_sched_barrier(0);
#pragma unroll
            for (int c = 0; c < 2; ++c) {
                short8 ap = *(const short8*)&P_lds[w][l15][c * 32 + quad * 8];
#pragma unroll
                for (int nt = 0; nt < 8; ++nt) {
                    short8 bv = *(const short8*)
                        &Vs[(nt * 16 + l15) * 64 + (((c * 4 + quad) ^ (l15 & 7)) * 8)];
                    oacc[nt] = __builtin_amdgcn_mfma_f32_16x16x32_bf16(
                        ap, bv, oacc[nt], 0, 0, 0);
                }
            }
        }
#pragma unroll
        for (int r = 0; r < 4; ++r) {
            float s = l_part[r];
            s += __shfl_xor(s, 1);
            s += __shfl_xor(s, 2);
            s += __shfl_xor(s, 4);
            s += __shfl_xor(s, 8);
            float inv = 1.f / s;
            int row = i0 + quad * 4 + r;
            float* dst = part + ((size_t)g * SEQ + row) * 1024 + h * 128;
#pragma unroll
            for (int nt = 0; nt < 8; ++nt) dst[nt * 16 + l15] = oacc[nt][r] * inv;
        }
    }
}

// attn_bf[s][c] = bf16( sum_g part[g][s][c] )
__global__ void sum4_bf_kernel(const float* __restrict__ part, ushort_t* __restrict__ attn) {
    int idx = blockIdx.x * 256 + threadIdx.x;
    const float4* p = (const float4*)part;
    float4 a = p[idx];
    float4 b = p[idx + 524288];
    float4 c = p[idx + 2 * 524288];
    float4 d = p[idx + 3 * 524288];
    union { ushort_t u[4]; unsigned long long ll; } pk;
    pk.u[0] = f2bf(a.x + b.x + c.x + d.x);
    pk.u[1] = f2bf(a.y + b.y + c.y + d.y);
    pk.u[2] = f2bf(a.z + b.z + c.z + d.z);
    pk.u[3] = f2bf(a.w + b.w + c.w + d.w);
    *(unsigned long long*)&attn[(size_t)idx * 4] = pk.ll;
}

extern "C" void kernel_launch(void* const* d_in, const int* in_sizes, int n_in,
                              void* d_out, int out_size, void* d_ws, size_t ws_size,
                              hipStream_t stream) {
    const float* x  = (const float*)d_in[0];
    const float* Wq = (const float*)d_in[1];
    const float* bq = (const float*)d_in[2];
    const float* Wk = (const float*)d_in[3];
    const float* bk = (const float*)d_in[4];
    const float* Wv = (const float*)d_in[5];
    const float* bv = (const float*)d_in[6];
    const float* Wo = (const float*)d_in[7];
    const float* bo = (const float*)d_in[8];
    const float* W1 = (const float*)d_in[9];
    const float* b1 = (const float*)d_in[10];
    const float* W2 = (const float*)d_in[11];
    const float* b2 = (const float*)d_in[12];
    float* out = (float*)d_out;

    // Workspace layout (MB offsets), 64 MB total, lifetime-overlapped (as R6).
    char* ws = (char*)d_ws;
#define MB(x) ((size_t)(x) << 20)
    float*    part    = (float*)(ws);
    ushort_t* W2_bf   = (ushort_t*)(ws);
    float*    qkv_f32 = (float*)(ws + MB(32));
    ushort_t* o_bf    = (ushort_t*)(ws + MB(32));
    ushort_t* attn_bf = (ushort_t*)(ws + MB(36));
    ushort_t* h1_bf   = (ushort_t*)(ws + MB(40));
    ushort_t* x_bf    = (ushort_t*)(ws + MB(48));
    ushort_t* q_bf    = (ushort_t*)(ws + MB(48));
    ushort_t* Wqkv_bf = (ushort_t*)(ws + MB(52));
    ushort_t* Wq_bf   = (ushort_t*)(ws + MB(52));
    ushort_t* Wk_bf   = (ushort_t*)(ws + MB(54));
    ushort_t* Wv_bf   = (ushort_t*)(ws + MB(55));
    ushort_t* k_bf    = (ushort_t*)(ws + MB(52));
    ushort_t* vT      = (ushort_t*)(ws + MB(54));
    ushort_t* Wo_bf   = (ushort_t*)(ws + MB(54));
    ushort_t* W1_bf   = (ushort_t*)(ws + MB(56));
#undef MB

    // ---- convert x, Wq, Wk, Wv, W1 to bf16 ----
    cvt_bf_kernel<<<8192, 256, 0, stream>>>(
        x, x_bf, 524288, Wq, Wq_bf, 262144, Wk, Wk_bf, 131072,
        Wv, Wv_bf, 131072, W1, W1_bf);
    // merged QKV projection
    mfma_gemm_kernel<false, float><<<256, 256, 0, stream>>>(
        x_bf, Wqkv_bf, bq, bk, bv, 1024, 1536, qkv_f32, SEQ, 2048, 1024, 16);
    // fused RoPE + V-transpose
    prep_kernel<<<2304, 256, 0, stream>>>(qkv_f32, q_bf, k_bf, vT);
    // flash attention + group sum
    mfma_attn_kernel<<<512, 256, 0, stream>>>(q_bf, k_bf, vT, part);
    sum4_bf_kernel<<<2048, 256, 0, stream>>>(part, attn_bf);
    // ---- convert Wo, W2 to bf16 (part/vT regions now dead) ----
    cvt_bf_kernel<<<17408, 256, 0, stream>>>(
        Wo, Wo_bf, 262144, W2, W2_bf, 4194304, W2, W2_bf, 0,
        W2, W2_bf, 0, W2, W2_bf);
    // output projection -> bf16 o
    mfma_gemm_kernel<false, ushort_t><<<128, 256, 0, stream>>>(
        attn_bf, Wo_bf, bo, bo, bo, 1024, 1024, o_bf, SEQ, 1024, 1024, 8);
    // MLP with pipelined GEMMs: W1+SiLU -> bf16 h1 ; W2 -> fp32 out
    mfma_gemm_pipe<true, ushort_t><<<256, 512, 0, stream>>>(
        o_bf, W1_bf, b1, h1_bf, SEQ, 4096, 1024, 32);
    mfma_gemm_pipe<false, float><<<256, 512, 0, stream>>>(
        h1_bf, W2_bf, b2, out, SEQ, 4096, 4096, 32);
}

// Round 8
// 382.712 us; speedup vs baseline: 1.0792x; 1.0792x over previous
//
#include <hip/hip_runtime.h>
#include <hip/hip_bf16.h>

#define SEQ 2048

typedef unsigned short ushort_t;
typedef __attribute__((ext_vector_type(8))) short short8;
typedef __attribute__((ext_vector_type(4))) float f32x4;

__device__ __forceinline__ ushort_t f2bf(float f) {
    __hip_bfloat16 h = __float2bfloat16(f);
    return *reinterpret_cast<ushort_t*>(&h);
}

__device__ __forceinline__ void st(float* p, float v) { *p = v; }
__device__ __forceinline__ void st(ushort_t* p, float v) { *p = f2bf(v); }

// async global->LDS, 16B per lane, wave-uniform LDS base + lane*16
__device__ __forceinline__ void gload16(const ushort_t* g, ushort_t* l) {
    __builtin_amdgcn_global_load_lds(
        (const __attribute__((address_space(1))) unsigned int*)g,
        (__attribute__((address_space(3))) unsigned int*)l, 16, 0, 0);
}

// ---- fp32 -> bf16 pack, up to 5 segments (sizes in float4 units) ----
__global__ void cvt_bf_kernel(const float* __restrict__ s0, ushort_t* __restrict__ d0, int n0,
                              const float* __restrict__ s1, ushort_t* __restrict__ d1, int n1,
                              const float* __restrict__ s2, ushort_t* __restrict__ d2, int n2,
                              const float* __restrict__ s3, ushort_t* __restrict__ d3, int n3,
                              const float* __restrict__ s4, ushort_t* __restrict__ d4) {
    int u = blockIdx.x * 256 + threadIdx.x;
    const float* s; ushort_t* d;
    if (u < n0) { s = s0; d = d0; }
    else if ((u -= n0) < n1) { s = s1; d = d1; }
    else if ((u -= n1) < n2) { s = s2; d = d2; }
    else if ((u -= n2) < n3) { s = s3; d = d3; }
    else { u -= n3; s = s4; d = d4; }
    float4 a = ((const float4*)s)[u];
    union { ushort_t us[4]; unsigned long long ll; } pk;
    pk.us[0] = f2bf(a.x); pk.us[1] = f2bf(a.y);
    pk.us[2] = f2bf(a.z); pk.us[3] = f2bf(a.w);
    ((unsigned long long*)d)[u] = pk.ll;
}

// ---- 128x128 m97-style GEMM (Wo / W1 / W2): BK=64, gload16, XOR swizzle,
// bijective XCD block swizzle. (Reverted to the R6 version: proven 763 TF.) ----
template <bool SILU, typename TC>
__global__ __launch_bounds__(256) void mfma_gemm_kernel(
    const ushort_t* __restrict__ A, const ushort_t* __restrict__ W,
    const float* __restrict__ bias, TC* __restrict__ C,
    int M, int N, int Kd, int NBX) {
    __shared__ __align__(16) ushort_t As[128 * 64];
    __shared__ __align__(16) ushort_t Bs[128 * 64];
    const int tid = threadIdx.x;
    const int w = tid >> 6, lane = tid & 63, l15 = lane & 15, quad = lane >> 4;
    const int nwg = gridDim.x;
    const int qq = nwg >> 3;
    const int bid = blockIdx.x;
    const int sw = (bid & 7) * qq + (bid >> 3);
    const int m0 = (sw / NBX) * 128, n0 = (sw % NBX) * 128;
    const int rw = (w >> 1) * 64, cw = (w & 1) * 64;
    const int rA = w * 32 + (lane >> 3);
    const int cch = ((lane & 7) ^ (lane >> 3)) * 8;

    f32x4 acc[4][4];
#pragma unroll
    for (int mt = 0; mt < 4; ++mt)
#pragma unroll
        for (int nt = 0; nt < 4; ++nt) acc[mt][nt] = (f32x4){0.f, 0.f, 0.f, 0.f};

    for (int k0 = 0; k0 < Kd; k0 += 64) {
#pragma unroll
        for (int c = 0; c < 4; ++c) {
            gload16(&A[(size_t)(m0 + rA + c * 8) * Kd + k0 + cch],
                    &As[(w * 4 + c) * 512]);
            gload16(&W[(size_t)(n0 + rA + c * 8) * Kd + k0 + cch],
                    &Bs[(w * 4 + c) * 512]);
        }
        __syncthreads();
#pragma unroll
        for (int kc = 0; kc < 2; ++kc) {
            short8 af[4], bfr[4];
#pragma unroll
            for (int mt = 0; mt < 4; ++mt) {
                int row = rw + mt * 16 + l15;
                int slot = (kc * 4 + quad) ^ (row & 7);
                af[mt] = *(const short8*)&As[row * 64 + slot * 8];
            }
#pragma unroll
            for (int nt = 0; nt < 4; ++nt) {
                int row = cw + nt * 16 + l15;
                int slot = (kc * 4 + quad) ^ (row & 7);
                bfr[nt] = *(const short8*)&Bs[row * 64 + slot * 8];
            }
#pragma unroll
            for (int mt = 0; mt < 4; ++mt)
#pragma unroll
                for (int nt = 0; nt < 4; ++nt)
                    acc[mt][nt] = __builtin_amdgcn_mfma_f32_16x16x32_bf16(
                        af[mt], bfr[nt], acc[mt][nt], 0, 0, 0);
        }
        __syncthreads();
    }
#pragma unroll
    for (int nt = 0; nt < 4; ++nt) {
        int col = n0 + cw + nt * 16 + l15;
        float bb = bias[col];
#pragma unroll
        for (int mt = 0; mt < 4; ++mt)
#pragma unroll
            for (int r = 0; r < 4; ++r) {
                int row = m0 + rw + mt * 16 + quad * 4 + r;
                float v = acc[mt][nt][r] + bb;
                if (SILU) v = v / (1.f + __expf(-v));
                st(&C[(size_t)row * N + col], v);
            }
    }
}

// ---- fused QKV GEMM: same m97 K-loop, but the epilogue applies RoPE (q,k)
// or the V-transpose directly -- qkv_f32 and the prep kernel are eliminated.
// Each 128-col block tile aligns exactly with one head. The f32 tile is
// staged through LDS (aliasing As/Bs, dead after the K-loop) in two 64-row
// halves for the cross-wave (idx, idx+64) rope pairing. ----
__global__ __launch_bounds__(256) void mfma_qkv_kernel(
    const ushort_t* __restrict__ A, const ushort_t* __restrict__ W,
    const float* __restrict__ bq, const float* __restrict__ bk,
    const float* __restrict__ bv,
    ushort_t* __restrict__ q_bf, ushort_t* __restrict__ k_bf,
    ushort_t* __restrict__ vT, int Kd) {
    __shared__ __align__(16) ushort_t smem[2 * 128 * 64];
    ushort_t* As = smem;
    ushort_t* Bs = smem + 128 * 64;
    float* Cs = (float*)smem;                    // 64 x 128 f32 (32 KB)
    const int tid = threadIdx.x;
    const int w = tid >> 6, lane = tid & 63, l15 = lane & 15, quad = lane >> 4;
    const int nwg = gridDim.x;
    const int qq = nwg >> 3;
    const int bid = blockIdx.x;
    const int sw = (bid & 7) * qq + (bid >> 3);
    const int m0 = (sw >> 4) * 128, n0 = (sw & 15) * 128;   // NBX = 16
    const int rw = (w >> 1) * 64, cw = (w & 1) * 64;
    const int rA = w * 32 + (lane >> 3);
    const int cch = ((lane & 7) ^ (lane >> 3)) * 8;

    f32x4 acc[4][4];
#pragma unroll
    for (int mt = 0; mt < 4; ++mt)
#pragma unroll
        for (int nt = 0; nt < 4; ++nt) acc[mt][nt] = (f32x4){0.f, 0.f, 0.f, 0.f};

    for (int k0 = 0; k0 < Kd; k0 += 64) {
#pragma unroll
        for (int c = 0; c < 4; ++c) {
            gload16(&A[(size_t)(m0 + rA + c * 8) * Kd + k0 + cch],
                    &As[(w * 4 + c) * 512]);
            gload16(&W[(size_t)(n0 + rA + c * 8) * Kd + k0 + cch],
                    &Bs[(w * 4 + c) * 512]);
        }
        __syncthreads();
#pragma unroll
        for (int kc = 0; kc < 2; ++kc) {
            short8 af[4], bfr[4];
#pragma unroll
            for (int mt = 0; mt < 4; ++mt) {
                int row = rw + mt * 16 + l15;
                int slot = (kc * 4 + quad) ^ (row & 7);
                af[mt] = *(const short8*)&As[row * 64 + slot * 8];
            }
#pragma unroll
            for (int nt = 0; nt < 4; ++nt) {
                int row = cw + nt * 16 + l15;
                int slot = (kc * 4 + quad) ^ (row & 7);
                bfr[nt] = *(const short8*)&Bs[row * 64 + slot * 8];
            }
#pragma unroll
            for (int mt = 0; mt < 4; ++mt)
#pragma unroll
                for (int nt = 0; nt < 4; ++nt)
                    acc[mt][nt] = __builtin_amdgcn_mfma_f32_16x16x32_bf16(
                        af[mt], bfr[nt], acc[mt][nt], 0, 0, 0);
        }
        __syncthreads();
    }

    // ---- fused epilogue: two 64-row halves through Cs ----
    const bool isq = n0 < 1024;
    const bool isv = n0 >= 1536;
    const int hhw = w >> 1;                      // wave's row-half
    union S8 { ushort_t u[8]; short8 v; };
#pragma unroll 1
    for (int hh = 0; hh < 2; ++hh) {
        if (hhw == hh) {
#pragma unroll
            for (int nt = 0; nt < 4; ++nt) {
                int col = cw + nt * 16 + l15;
                int gcol = n0 + col;
                float bb = gcol < 1024 ? bq[gcol]
                         : (gcol < 1536 ? bk[gcol - 1024] : bv[gcol - 1536]);
#pragma unroll
                for (int mt = 0; mt < 4; ++mt)
#pragma unroll
                    for (int r = 0; r < 4; ++r)
                        Cs[(mt * 16 + quad * 4 + r) * 128 + col] = acc[mt][nt][r] + bb;
            }
        }
        __syncthreads();
        const int srow0 = m0 + hh * 64;
        if (!isv) {
            // rope: 64 rows x 8 idx-chunks = 512 units, 2 per thread
            const int hd = (n0 >> 7) & 7;        // head (q: 0-7, k: 0-3)
            const float sc = isq ? 0.08838834764831845f : 1.f;
            for (int uu = tid; uu < 512; uu += 256) {
                int row = uu >> 3, ic = uu & 7;
                int s = srow0 + row;
                float t = (float)s;
                S8 o1, o2;
#pragma unroll
                for (int j = 0; j < 8; ++j) {
                    int idx = ic * 8 + j;
                    float invf = exp2f(-(float)idx * 0.20762050593f);
                    float ang = t * invf;
                    float c = cosf(ang), sn = sinf(ang);
                    float x1 = Cs[row * 128 + idx];
                    float x2 = Cs[row * 128 + idx + 64];
                    o1.u[j] = f2bf((x1 * c - x2 * sn) * sc);
                    o2.u[j] = f2bf((x2 * c + x1 * sn) * sc);
                }
                ushort_t* dst = isq ? (q_bf + (size_t)s * 1024 + hd * 128)
                                    : (k_bf + (size_t)s * 512 + hd * 128);
                *(short8*)(dst + ic * 8) = o1.v;
                *(short8*)(dst + ic * 8 + 64) = o2.v;
            }
        } else {
            // V-transpose: 128 d x 8 s-chunks = 1024 units, 4 per thread
            const int g = (n0 - 1536) >> 7;
            for (int uu = tid; uu < 1024; uu += 256) {
                int d = uu >> 3, sc8 = uu & 7;
                S8 o;
#pragma unroll
                for (int j = 0; j < 8; ++j)
                    o.u[j] = f2bf(Cs[(sc8 * 8 + j) * 128 + d]);
                *(short8*)&vT[(size_t)(g * 128 + d) * 2048 + srow0 + sc8 * 8] = o.v;
            }
        }
        __syncthreads();
    }
}

// MFMA flash attention, fixed-base softmax + XOR-swizzled K/V LDS (unchanged).
__global__ __launch_bounds__(256, 2) void mfma_attn_kernel(
    const ushort_t* __restrict__ qb, const ushort_t* __restrict__ kb,
    const ushort_t* __restrict__ vT, float* __restrict__ part) {
    const int tid = threadIdx.x;
    const int w = tid >> 6;
    const int lane = tid & 63;
    const int l15 = lane & 15;
    const int quad = lane >> 4;
    const int bx = blockIdx.x;
    const int pr = bx >> 3;
    const int g = (bx >> 1) & 3;
    const int h = (bx & 1) * 4 + w;

    const ushort_t* vtg = vT + (size_t)g * 128 * 2048;

    __shared__ __align__(16) ushort_t Ks[64 * 128];
    __shared__ __align__(16) ushort_t Vs[128 * 64];
    __shared__ __align__(16) ushort_t P_lds[4][16][72];

#pragma unroll 1
    for (int half = 0; half < 2; ++half) {
        const int p = half ? (127 - pr) : pr;
        const int i0 = p << 4;
        const int jmax = p >> 2;
        const int rbase = (p & 3) << 4;

        short8 aq[4];
        {
            const ushort_t* qrow = qb + (size_t)(i0 + l15) * 1024 + h * 128 + quad * 8;
#pragma unroll
            for (int kc = 0; kc < 4; ++kc) aq[kc] = *(const short8*)(qrow + kc * 32);
        }
        f32x4 oacc[8];
#pragma unroll
        for (int nt = 0; nt < 8; ++nt) oacc[nt] = (f32x4){0.f, 0.f, 0.f, 0.f};
        float l_part[4] = {0.f, 0.f, 0.f, 0.f};

        short8 kreg[4], vreg[4];
#pragma unroll
        for (int it = 0; it < 4; ++it) {
            int fl = it * 256 + tid;
            int r = fl >> 4, c8 = fl & 15;
            kreg[it] = *(const short8*)&kb[(size_t)r * 512 + g * 128 + c8 * 8];
        }
#pragma unroll
        for (int it = 0; it < 4; ++it) {
            int fl = it * 256 + tid;
            int r = fl >> 3, c8 = fl & 7;
            vreg[it] = *(const short8*)&vtg[(size_t)r * 2048 + c8 * 8];
        }

        for (int jt = 0; jt <= jmax; ++jt) {
            __syncthreads();
#pragma unroll
            for (int it = 0; it < 4; ++it) {
                int fl = it * 256 + tid;
                int r = fl >> 4, c8 = fl & 15;
                *(short8*)&Ks[r * 128 + ((c8 ^ (r & 7)) * 8)] = kreg[it];
            }
#pragma unroll
            for (int it = 0; it < 4; ++it) {
                int fl = it * 256 + tid;
                int r = fl >> 3, c8 = fl & 7;
                *(short8*)&Vs[r * 64 + ((c8 ^ (r & 7)) * 8)] = vreg[it];
            }
            __syncthreads();
            if (jt < jmax) {
                const int j1 = (jt + 1) << 6;
#pragma unroll
                for (int it = 0; it < 4; ++it) {
                    int fl = it * 256 + tid;
                    int r = fl >> 4, c8 = fl & 15;
                    kreg[it] = *(const short8*)&kb[(size_t)(j1 + r) * 512 + g * 128 + c8 * 8];
                }
#pragma unroll
                for (int it = 0; it < 4; ++it) {
                    int fl = it * 256 + tid;
                    int r = fl >> 3, c8 = fl & 7;
                    vreg[it] = *(const short8*)&vtg[(size_t)r * 2048 + j1 + c8 * 8];
                }
            }
            f32x4 sacc[4];
#pragma unroll
            for (int nt = 0; nt < 4; ++nt) sacc[nt] = (f32x4){0.f, 0.f, 0.f, 0.f};
#pragma unroll
            for (int nt = 0; nt < 4; ++nt) {
                const ushort_t* krow = &Ks[(nt * 16 + l15) * 128];
                const int sw = l15 & 7;
#pragma unroll
                for (int kc = 0; kc < 4; ++kc) {
                    short8 bk = *(const short8*)(krow + (((kc * 4 + quad) ^ sw) * 8));
                    sacc[nt] = __builtin_amdgcn_mfma_f32_16x16x32_bf16(
                        aq[kc], bk, sacc[nt], 0, 0, 0);
                }
            }
            if (jt == jmax) {
#pragma unroll
                for (int nt = 0; nt < 4; ++nt) {
                    int colg = nt * 16 + l15;
#pragma unroll
                    for (int r = 0; r < 4; ++r) {
                        int rowg = rbase + quad * 4 + r;
                        if (colg > rowg) sacc[nt][r] = -1e30f;
                    }
                }
            }
#pragma unroll
            for (int nt = 0; nt < 4; ++nt)
#pragma unroll
                for (int r = 0; r < 4; ++r) {
                    float e = __expf(sacc[nt][r] - 14.f);
                    sacc[nt][r] = e;
                    l_part[r] += e;
                }
#pragma unroll
            for (int nt = 0; nt < 4; ++nt)
#pragma unroll
                for (int r = 0; r < 4; ++r)
                    P_lds[w][quad * 4 + r][nt * 16 + l15] = f2bf(sacc[nt][r]);
            asm volatile("s_waitcnt lgkmcnt(0)" ::: "memory");
            __builtin_amdgcn_sched_barrier(0);
#pragma unroll
            for (int c = 0; c < 2; ++c) {
                short8 ap = *(const short8*)&P_lds[w][l15][c * 32 + quad * 8];
#pragma unroll
                for (int nt = 0; nt < 8; ++nt) {
                    short8 bv = *(const short8*)
                        &Vs[(nt * 16 + l15) * 64 + (((c * 4 + quad) ^ (l15 & 7)) * 8)];
                    oacc[nt] = __builtin_amdgcn_mfma_f32_16x16x32_bf16(
                        ap, bv, oacc[nt], 0, 0, 0);
                }
            }
        }
#pragma unroll
        for (int r = 0; r < 4; ++r) {
            float s = l_part[r];
            s += __shfl_xor(s, 1);
            s += __shfl_xor(s, 2);
            s += __shfl_xor(s, 4);
            s += __shfl_xor(s, 8);
            float inv = 1.f / s;
            int row = i0 + quad * 4 + r;
            float* dst = part + ((size_t)g * SEQ + row) * 1024 + h * 128;
#pragma unroll
            for (int nt = 0; nt < 8; ++nt) dst[nt * 16 + l15] = oacc[nt][r] * inv;
        }
    }
}

// attn_bf[s][c] = bf16( sum_g part[g][s][c] )
__global__ void sum4_bf_kernel(const float* __restrict__ part, ushort_t* __restrict__ attn) {
    int idx = blockIdx.x * 256 + threadIdx.x;
    const float4* p = (const float4*)part;
    float4 a = p[idx];
    float4 b = p[idx + 524288];
    float4 c = p[idx + 2 * 524288];
    float4 d = p[idx + 3 * 524288];
    union { ushort_t u[4]; unsigned long long ll; } pk;
    pk.u[0] = f2bf(a.x + b.x + c.x + d.x);
    pk.u[1] = f2bf(a.y + b.y + c.y + d.y);
    pk.u[2] = f2bf(a.z + b.z + c.z + d.z);
    pk.u[3] = f2bf(a.w + b.w + c.w + d.w);
    *(unsigned long long*)&attn[(size_t)idx * 4] = pk.ll;
}

extern "C" void kernel_launch(void* const* d_in, const int* in_sizes, int n_in,
                              void* d_out, int out_size, void* d_ws, size_t ws_size,
                              hipStream_t stream) {
    const float* x  = (const float*)d_in[0];
    const float* Wq = (const float*)d_in[1];
    const float* bq = (const float*)d_in[2];
    const float* Wk = (const float*)d_in[3];
    const float* bk = (const float*)d_in[4];
    const float* Wv = (const float*)d_in[5];
    const float* bv = (const float*)d_in[6];
    const float* Wo = (const float*)d_in[7];
    const float* bo = (const float*)d_in[8];
    const float* W1 = (const float*)d_in[9];
    const float* b1 = (const float*)d_in[10];
    const float* W2 = (const float*)d_in[11];
    const float* b2 = (const float*)d_in[12];
    float* out = (float*)d_out;

    // Workspace layout (MB offsets), 64 MB, lifetime-overlapped:
    //  0-32  part (attn->sum4)        -> W2_bf (cvt2) after sum4
    // 32-36  x_bf (cvt1->QKV)         -> o_bf (Wo out) after
    // 36-40  Wqkv_bf (cvt1->QKV)      -> attn_bf (sum4 out) after
    // 40-44  q_bf, 44-46 k_bf, 46-48 vT (QKV out -> attn)
    // 48-50  Wo_bf (cvt2 -> Wo GEMM)
    // 40-56  h1_bf (W1 out; q/k/vT/Wo_bf all dead by then)
    // 56-64  W1_bf (cvt1 -> W1 GEMM)
    char* ws = (char*)d_ws;
#define MB(x) ((size_t)(x) << 20)
    float*    part    = (float*)(ws);
    ushort_t* W2_bf   = (ushort_t*)(ws);
    ushort_t* x_bf    = (ushort_t*)(ws + MB(32));
    ushort_t* o_bf    = (ushort_t*)(ws + MB(32));
    ushort_t* Wqkv_bf = (ushort_t*)(ws + MB(36));
    ushort_t* Wq_bf   = (ushort_t*)(ws + MB(36));
    ushort_t* Wk_bf   = (ushort_t*)(ws + MB(38));
    ushort_t* Wv_bf   = (ushort_t*)(ws + MB(39));
    ushort_t* attn_bf = (ushort_t*)(ws + MB(36));
    ushort_t* q_bf    = (ushort_t*)(ws + MB(40));
    ushort_t* k_bf    = (ushort_t*)(ws + MB(44));
    ushort_t* vT      = (ushort_t*)(ws + MB(46));
    ushort_t* Wo_bf   = (ushort_t*)(ws + MB(48));
    ushort_t* h1_bf   = (ushort_t*)(ws + MB(40));
    ushort_t* W1_bf   = (ushort_t*)(ws + MB(56));
#undef MB

    // ---- convert x, Wq, Wk, Wv, W1 to bf16 ----
    cvt_bf_kernel<<<8192, 256, 0, stream>>>(
        x, x_bf, 524288, Wq, Wq_bf, 262144, Wk, Wk_bf, 131072,
        Wv, Wv_bf, 131072, W1, W1_bf);
    // fused QKV projection + RoPE + V-transpose (one dispatch)
    mfma_qkv_kernel<<<256, 256, 0, stream>>>(
        x_bf, Wqkv_bf, bq, bk, bv, q_bf, k_bf, vT, 1024);
    // flash attention + group sum
    mfma_attn_kernel<<<512, 256, 0, stream>>>(q_bf, k_bf, vT, part);
    sum4_bf_kernel<<<2048, 256, 0, stream>>>(part, attn_bf);
    // ---- convert Wo, W2 to bf16 (part region now dead) ----
    cvt_bf_kernel<<<17408, 256, 0, stream>>>(
        Wo, Wo_bf, 262144, W2, W2_bf, 4194304, W2, W2_bf, 0,
        W2, W2_bf, 0, W2, W2_bf);
    // output projection -> bf16 o
    mfma_gemm_kernel<false, ushort_t><<<128, 256, 0, stream>>>(
        attn_bf, Wo_bf, bo, o_bf, SEQ, 1024, 1024, 8);
    // MLP: W1+SiLU -> bf16 h1 ; W2 -> fp32 out
    mfma_gemm_kernel<true, ushort_t><<<512, 256, 0, stream>>>(
        o_bf, W1_bf, b1, h1_bf, SEQ, 4096, 1024, 32);
    mfma_gemm_kernel<false, float><<<512, 256, 0, stream>>>(
        h1_bf, W2_bf, b2, out, SEQ, 4096, 4096, 32);
}